// Round 1
// baseline (969.765 us; speedup 1.0000x reference)
//
#include <hip/hip_runtime.h>

#define NN 100000
#define NE 1600000
#define WT 12
#define CI 16
#define CM 32
#define CO 32

// ---------------- K1: histogram counts + weighted in-degree ----------------
__global__ void k_count(const int* __restrict__ A, const float* __restrict__ ew,
                        int* __restrict__ cnt, float* __restrict__ deg) {
    int e = blockIdx.x * 256 + threadIdx.x;
    if (e >= NE) return;
    int c = A[NE + e];
    atomicAdd(&cnt[c], 1);
    atomicAdd(&deg[c], ew[e]);
}

// ---------------- K2: dis = rsqrt(deg), segment allocation (wave-scan) -----
__global__ void k_dis_alloc(const float* __restrict__ deg, const int* __restrict__ cnt,
                            float* __restrict__ dis, int* __restrict__ start,
                            int* __restrict__ total) {
    int n = blockIdx.x * 256 + threadIdx.x;
    bool valid = (n < NN);
    int c = valid ? cnt[n] : 0;
    if (valid) {
        float d = deg[n];
        dis[n] = d > 0.0f ? rsqrtf(d) : 0.0f;
    }
    // wave-level inclusive scan of c
    int lane = threadIdx.x & 63;
    int inc = c;
    #pragma unroll
    for (int o = 1; o < 64; o <<= 1) {
        int v = __shfl_up(inc, o, 64);
        if (lane >= o) inc += v;
    }
    int base = 0;
    if (lane == 63) base = atomicAdd(total, inc);   // one atomic per wave
    base = __shfl(base, 63, 64);
    if (valid) start[n] = base + inc - c;
}

// ---------------- K3: scatter edges into per-dst segments ------------------
__global__ void k_scatter(const int* __restrict__ A, const float* __restrict__ ew,
                          const float* __restrict__ dis, const int* __restrict__ start,
                          int* __restrict__ fill, int* __restrict__ src_s,
                          float* __restrict__ nrm_s) {
    int e = blockIdx.x * 256 + threadIdx.x;
    if (e >= NE) return;
    int r = A[e];
    int c = A[NE + e];
    float nrm = dis[r] * ew[e] * dis[c];
    int p = start[c] + atomicAdd(&fill[c], 1);
    src_s[p] = r;
    nrm_s[p] = nrm;
}

// ---------------- K4: aggregation, one wave per dst node -------------------
// x layout: [t][n][ci] (t-major). Lane l covers (t = p*4 + l/16, ci = l%16),
// p = 0..2, so the 64-lane wave covers all 192 (t,ci) pairs.
// xagg layout: [n][t][ci]  (node-major, 192 floats contiguous per node)
__global__ void k_agg(const float* __restrict__ x, const int* __restrict__ start,
                      const int* __restrict__ cnt, const int* __restrict__ src_s,
                      const float* __restrict__ nrm_s, float* __restrict__ xagg) {
    int wave = threadIdx.x >> 6;
    int lane = threadIdx.x & 63;
    int node = blockIdx.x * 4 + wave;
    if (node >= NN) return;
    int s = start[node];
    int c = cnt[node];
    int ci = lane & 15;
    int th = lane >> 4;           // 0..3
    int o0 = (0 * 4 + th) * (NN * CI) + ci;
    int o1 = (1 * 4 + th) * (NN * CI) + ci;
    int o2 = (2 * 4 + th) * (NN * CI) + ci;
    float a0 = 0.0f, a1 = 0.0f, a2 = 0.0f;
    for (int i = 0; i < c; i++) {
        int src = src_s[s + i];           // broadcast load (same addr all lanes)
        float w = nrm_s[s + i];
        int b = src * CI;
        a0 += w * x[o0 + b];
        a1 += w * x[o1 + b];
        a2 += w * x[o2 + b];
    }
    float* o = &xagg[node * (WT * CI)];
    o[lane]       = a0;   // (t,ci) flat index = t*16+ci = p*64 + lane
    o[64 + lane]  = a1;
    o[128 + lane] = a2;
}

// ---------------- K5a: fold GCN weight into conv weight --------------------
// M2[t][k*16+ci][co] = sum_cm gw[t+k-1][ci][cm] * cw[co][cm][k]   (0 if t+k-1 invalid)
__global__ void k_foldW(const float* __restrict__ gw, const float* __restrict__ cw,
                        float* __restrict__ M2) {
    int i = blockIdx.x * 256 + threadIdx.x;
    if (i >= WT * 3 * CI * CO) return;
    int co = i & 31;
    int rem = i >> 5;            // t*48 + k*16 + ci
    int ci = rem & 15;
    int kidx = rem % 48;
    int k = kidx >> 4;
    int t = rem / 48;
    int tp = t + k - 1;
    float s = 0.0f;
    if (tp >= 0 && tp < WT) {
        for (int cm = 0; cm < CM; cm++)
            s += gw[(tp * CI + ci) * CM + cm] * cw[co * (CM * 3) + cm * 3 + k];
    }
    M2[i] = s;
}

// ---------------- K5b: fold biases -----------------------------------------
__global__ void k_foldB(const float* __restrict__ gb, const float* __restrict__ cw,
                        const float* __restrict__ cb, float* __restrict__ B2) {
    int i = blockIdx.x * 256 + threadIdx.x;
    if (i >= WT * CO) return;
    int co = i & 31;
    int t = i >> 5;
    float s = cb[co];
    for (int k = 0; k < 3; k++) {
        int tp = t + k - 1;
        if (tp < 0 || tp >= WT) continue;
        for (int cm = 0; cm < CM; cm++)
            s += gb[tp * CM + cm] * cw[co * (CM * 3) + cm * 3 + k];
    }
    B2[i] = s;
}

// ---------------- K7: fused GEMM + temporal conv + bias + LeakyReLU --------
// grid (ceil(N/256), 12); t fixed per block; thread = node; 32 acc regs.
__global__ __launch_bounds__(256) void k_out(const float* __restrict__ xagg,
                                             const float* __restrict__ M2,
                                             const float* __restrict__ B2,
                                             float* __restrict__ out) {
    __shared__ float Ml[48 * CO];
    __shared__ float Bl[CO];
    int t = blockIdx.y;
    for (int i = threadIdx.x; i < 48 * CO; i += 256) Ml[i] = M2[t * (48 * CO) + i];
    if (threadIdx.x < CO) Bl[threadIdx.x] = B2[t * CO + threadIdx.x];
    __syncthreads();
    int n = blockIdx.x * 256 + threadIdx.x;
    if (n >= NN) return;

    const float* xr = &xagg[n * (WT * CI)];
    float xv[48];
    #pragma unroll
    for (int j = 0; j < 16; j++) xv[j]      = (t >= 1)      ? xr[(t - 1) * CI + j] : 0.0f;
    #pragma unroll
    for (int j = 0; j < 16; j++) xv[16 + j] = xr[t * CI + j];
    #pragma unroll
    for (int j = 0; j < 16; j++) xv[32 + j] = (t < WT - 1)  ? xr[(t + 1) * CI + j] : 0.0f;

    float acc[CO];
    #pragma unroll
    for (int co = 0; co < CO; co++) acc[co] = Bl[co];
    #pragma unroll
    for (int kk = 0; kk < 48; kk++) {
        float a = xv[kk];
        #pragma unroll
        for (int co = 0; co < CO; co++) acc[co] += a * Ml[kk * CO + co];
    }
    float* o = &out[(n * WT + t) * CO];
    #pragma unroll
    for (int co = 0; co < CO; co++) {
        float v = acc[co];
        o[co] = v >= 0.0f ? v : 0.01f * v;
    }
}

// ---------------- launch ----------------------------------------------------
extern "C" void kernel_launch(void* const* d_in, const int* in_sizes, int n_in,
                              void* d_out, int out_size, void* d_ws, size_t ws_size,
                              hipStream_t stream) {
    const float* x  = (const float*)d_in[0];
    const int*   A  = (const int*)d_in[1];
    const float* ew = (const float*)d_in[2];
    const float* gw = (const float*)d_in[3];
    const float* gb = (const float*)d_in[4];
    const float* cw = (const float*)d_in[5];
    const float* cb = (const float*)d_in[6];
    float* out = (float*)d_out;
    float* ws  = (float*)d_ws;

    // ws layout (floats; all 16-elem aligned):
    // [deg N][cnt N][fill N][total 64][dis N][start N][src_s E][nrm_s E]
    // [M2 18432][B2 384][xagg N*192]
    float* deg   = ws;
    int*   cnt   = (int*)(ws + NN);
    int*   fill  = (int*)(ws + 2 * NN);
    int*   total = (int*)(ws + 3 * NN);
    float* dis   = ws + 3 * NN + 64;
    int*   start = (int*)(ws + 4 * NN + 64);
    int*   src_s = (int*)(ws + 5 * NN + 64);
    float* nrm_s = ws + 5 * NN + 64 + NE;
    float* M2    = ws + 5 * NN + 64 + 2 * NE;
    float* B2    = M2 + WT * 3 * CI * CO;
    float* xagg  = B2 + WT * CO;

    // zero the atomics region: deg, cnt, fill, total
    hipMemsetAsync(d_ws, 0, (size_t)(3 * NN + 64) * sizeof(float), stream);

    k_count   <<<(NE + 255) / 256, 256, 0, stream>>>(A, ew, cnt, deg);
    k_dis_alloc<<<(NN + 255) / 256, 256, 0, stream>>>(deg, cnt, dis, start, total);
    k_scatter <<<(NE + 255) / 256, 256, 0, stream>>>(A, ew, dis, start, fill, src_s, nrm_s);
    k_agg     <<<NN / 4, 256, 0, stream>>>(x, start, cnt, src_s, nrm_s, xagg);
    k_foldW   <<<(WT * 3 * CI * CO + 255) / 256, 256, 0, stream>>>(gw, cw, M2);
    k_foldB   <<<(WT * CO + 255) / 256, 256, 0, stream>>>(gb, cw, cb, B2);
    k_out     <<<dim3((NN + 255) / 256, WT), 256, 0, stream>>>(xagg, M2, B2, out);
}

// Round 2
// 712.738 us; speedup vs baseline: 1.3606x; 1.3606x over previous
//
#include <hip/hip_runtime.h>

#define NN 100000
#define NE 1600000
#define WT 12
#define CI 16
#define CM 32
#define CO 32

// ---- bf16 pack (round-to-nearest-even), 2 channels per uint ---------------
__device__ __forceinline__ unsigned bf16pack(float a, float b) {
    unsigned ua = __float_as_uint(a);
    unsigned ub = __float_as_uint(b);
    ua = (ua + 0x7FFFu + ((ua >> 16) & 1u)) >> 16;
    ub = (ub + 0x7FFFu + ((ub >> 16) & 1u)) >> 16;
    return ua | (ub << 16);
}

// ---------------- K0: transpose x [t][n][ci] -> xTb [n][96 uints] ----------
// uint u at [n][q]: q = t*8+p holds bf16(x[t][n][2p]), bf16(x[t][n][2p+1])
__global__ void k_xpose(const float* __restrict__ x, unsigned* __restrict__ xTb) {
    int f = blockIdx.x * 256 + threadIdx.x;            // over NN*96
    if (f >= NN * 96) return;
    int n = f / 96;
    int u = f - n * 96;
    int t = u >> 3;
    int p = u & 7;
    const float2* x2 = (const float2*)x;
    float2 v = x2[((size_t)t * NN + n) * 8 + p];
    xTb[f] = bf16pack(v.x, v.y);
}

// ---------------- K1: histogram counts + weighted in-degree ----------------
__global__ void k_count(const int* __restrict__ A, const float* __restrict__ ew,
                        int* __restrict__ cnt, float* __restrict__ deg) {
    int e = blockIdx.x * 256 + threadIdx.x;
    if (e >= NE) return;
    int c = A[NE + e];
    atomicAdd(&cnt[c], 1);
    atomicAdd(&deg[c], ew[e]);
}

// ---------------- K2: dis = rsqrt(deg), segment allocation (wave-scan) -----
__global__ void k_dis_alloc(const float* __restrict__ deg, const int* __restrict__ cnt,
                            float* __restrict__ dis, int* __restrict__ start,
                            int* __restrict__ total) {
    int n = blockIdx.x * 256 + threadIdx.x;
    bool valid = (n < NN);
    int c = valid ? cnt[n] : 0;
    if (valid) {
        float d = deg[n];
        dis[n] = d > 0.0f ? rsqrtf(d) : 0.0f;
    }
    int lane = threadIdx.x & 63;
    int inc = c;
    #pragma unroll
    for (int o = 1; o < 64; o <<= 1) {
        int v = __shfl_up(inc, o, 64);
        if (lane >= o) inc += v;
    }
    int base = 0;
    if (lane == 63) base = atomicAdd(total, inc);   // one atomic per wave
    base = __shfl(base, 63, 64);
    if (valid) start[n] = base + inc - c;
}

// ---------------- K3: scatter edges into per-dst segments (8B combined) ----
__global__ void k_scatter(const int* __restrict__ A, const float* __restrict__ ew,
                          const float* __restrict__ dis, const int* __restrict__ start,
                          int* __restrict__ fill, float2* __restrict__ meta) {
    int e = blockIdx.x * 256 + threadIdx.x;
    if (e >= NE) return;
    int r = A[e];
    int c = A[NE + e];
    float nrm = dis[r] * ew[e] * dis[c];
    int p = start[c] + atomicAdd(&fill[c], 1);
    meta[p] = make_float2(__int_as_float(r), nrm);
}

// ---------------- K4: aggregation, one wave per dst node -------------------
// xTb: [src][96] uints, contiguous 384 B per node.
// Per edge: load u0 = row[lane] (256 B coalesced), u1 = row[64 + (lane&31)]
// (lanes 32-63 read the same 128 B as 0-31 -> merged). fp32 accumulate.
// xagg out: [n][t][ci] fp32, written as float2 pairs (q = t*8 + ci/2).
__global__ __launch_bounds__(256) void k_agg(const unsigned* __restrict__ xTb,
                      const int* __restrict__ start, const int* __restrict__ cnt,
                      const float2* __restrict__ meta, float* __restrict__ xagg) {
    int wave = threadIdx.x >> 6;
    int lane = threadIdx.x & 63;
    int node = blockIdx.x * 4 + wave;
    if (node >= NN) return;
    int s = start[node];
    int c = cnt[node];
    int l32 = lane & 31;
    float a0x = 0.0f, a0y = 0.0f, a1x = 0.0f, a1y = 0.0f;
    const float2* mp = meta + s;
    #pragma unroll 2
    for (int i = 0; i < c; i++) {
        float2 m = mp[i];                       // broadcast 8B
        int src = __float_as_int(m.x);
        float w = m.y;
        const unsigned* row = xTb + (size_t)src * 96;
        unsigned u0 = row[lane];
        unsigned u1 = row[64 + l32];
        a0x += w * __uint_as_float(u0 << 16);
        a0y += w * __uint_as_float(u0 & 0xFFFF0000u);
        a1x += w * __uint_as_float(u1 << 16);
        a1y += w * __uint_as_float(u1 & 0xFFFF0000u);
    }
    float2* o2 = (float2*)(xagg + (size_t)node * 192);
    o2[lane] = make_float2(a0x, a0y);
    if (lane < 32) o2[64 + lane] = make_float2(a1x, a1y);
}

// ---------------- K5a: fold GCN weight into conv weight --------------------
// M2[t][k*16+ci][co] = sum_cm gw[t+k-1][ci][cm] * cw[co][cm][k]
__global__ void k_foldW(const float* __restrict__ gw, const float* __restrict__ cw,
                        float* __restrict__ M2) {
    int i = blockIdx.x * 256 + threadIdx.x;
    if (i >= WT * 3 * CI * CO) return;
    int co = i & 31;
    int rem = i >> 5;            // t*48 + k*16 + ci
    int ci = rem & 15;
    int kidx = rem % 48;
    int k = kidx >> 4;
    int t = rem / 48;
    int tp = t + k - 1;
    float s = 0.0f;
    if (tp >= 0 && tp < WT) {
        for (int cm = 0; cm < CM; cm++)
            s += gw[(tp * CI + ci) * CM + cm] * cw[co * (CM * 3) + cm * 3 + k];
    }
    M2[i] = s;
}

// ---------------- K5b: fold biases -----------------------------------------
__global__ void k_foldB(const float* __restrict__ gb, const float* __restrict__ cw,
                        const float* __restrict__ cb, float* __restrict__ B2) {
    int i = blockIdx.x * 256 + threadIdx.x;
    if (i >= WT * CO) return;
    int co = i & 31;
    int t = i >> 5;
    float s = cb[co];
    for (int k = 0; k < 3; k++) {
        int tp = t + k - 1;
        if (tp < 0 || tp >= WT) continue;
        for (int cm = 0; cm < CM; cm++)
            s += gb[tp * CM + cm] * cw[co * (CM * 3) + cm * 3 + k];
    }
    B2[i] = s;
}

// ---------------- K7: all-t GEMM epilogue, scalar weights, no LDS ----------
// Thread = node. Rolling 48-float window (prv/cur/nxt) over the node's 192-
// float xagg row; weights read via wave-uniform addresses -> s_load + v_fmac
// with SGPR operand. xagg read ONCE per node (77 MB total).
__global__ __launch_bounds__(64) void k_out(const float* __restrict__ xagg,
                                            const float* __restrict__ M2,
                                            const float* __restrict__ B2,
                                            float* __restrict__ out) {
    int n = blockIdx.x * 64 + threadIdx.x;
    if (n >= NN) return;
    const float4* xr = (const float4*)(xagg + (size_t)n * 192);
    float prv[16], cur[16], nxt[16];
    #pragma unroll
    for (int j = 0; j < 16; j++) prv[j] = 0.0f;
    #pragma unroll
    for (int q = 0; q < 4; q++) {
        float4 v = xr[q];
        cur[4*q] = v.x; cur[4*q+1] = v.y; cur[4*q+2] = v.z; cur[4*q+3] = v.w;
    }
    #pragma unroll
    for (int q = 0; q < 4; q++) {
        float4 v = xr[4 + q];
        nxt[4*q] = v.x; nxt[4*q+1] = v.y; nxt[4*q+2] = v.z; nxt[4*q+3] = v.w;
    }
    #pragma unroll 1
    for (int t = 0; t < WT; t++) {
        const float* Wt = M2 + (size_t)t * 48 * CO;     // uniform -> s_load
        float acc[CO];
        #pragma unroll
        for (int co = 0; co < CO; co++) acc[co] = B2[t * CO + co];
        #pragma unroll
        for (int j = 0; j < 16; j++) {
            float a = prv[j];
            #pragma unroll
            for (int co = 0; co < CO; co++) acc[co] += a * Wt[j * CO + co];
        }
        #pragma unroll
        for (int j = 0; j < 16; j++) {
            float a = cur[j];
            #pragma unroll
            for (int co = 0; co < CO; co++) acc[co] += a * Wt[(16 + j) * CO + co];
        }
        #pragma unroll
        for (int j = 0; j < 16; j++) {
            float a = nxt[j];
            #pragma unroll
            for (int co = 0; co < CO; co++) acc[co] += a * Wt[(32 + j) * CO + co];
        }
        float* o = out + ((size_t)n * WT + t) * CO;
        #pragma unroll
        for (int co = 0; co < CO; co += 4) {
            float4 v;
            v.x = acc[co]     >= 0.0f ? acc[co]     : 0.01f * acc[co];
            v.y = acc[co + 1] >= 0.0f ? acc[co + 1] : 0.01f * acc[co + 1];
            v.z = acc[co + 2] >= 0.0f ? acc[co + 2] : 0.01f * acc[co + 2];
            v.w = acc[co + 3] >= 0.0f ? acc[co + 3] : 0.01f * acc[co + 3];
            *(float4*)(o + co) = v;
        }
        #pragma unroll
        for (int j = 0; j < 16; j++) { prv[j] = cur[j]; cur[j] = nxt[j]; }
        if (t < WT - 2) {
            #pragma unroll
            for (int q = 0; q < 4; q++) {
                float4 v = xr[(t + 2) * 4 + q];
                nxt[4*q] = v.x; nxt[4*q+1] = v.y; nxt[4*q+2] = v.z; nxt[4*q+3] = v.w;
            }
        } else {
            #pragma unroll
            for (int j = 0; j < 16; j++) nxt[j] = 0.0f;
        }
    }
}

// ---------------- launch ----------------------------------------------------
extern "C" void kernel_launch(void* const* d_in, const int* in_sizes, int n_in,
                              void* d_out, int out_size, void* d_ws, size_t ws_size,
                              hipStream_t stream) {
    const float* x  = (const float*)d_in[0];
    const int*   A  = (const int*)d_in[1];
    const float* ew = (const float*)d_in[2];
    const float* gw = (const float*)d_in[3];
    const float* gb = (const float*)d_in[4];
    const float* cw = (const float*)d_in[5];
    const float* cb = (const float*)d_in[6];
    float* out = (float*)d_out;
    float* ws  = (float*)d_ws;

    // ws layout (floats):
    // [deg N][cnt N][fill N][total 64][dis N][start N]
    // [meta 2E (float2)][xTb N*96 (uint)][M2 18432][B2 384][xagg N*192]
    float*    deg   = ws;
    int*      cnt   = (int*)(ws + NN);
    int*      fill  = (int*)(ws + 2 * NN);
    int*      total = (int*)(ws + 3 * NN);
    float*    dis   = ws + 3 * NN + 64;
    int*      start = (int*)(ws + 4 * NN + 64);
    float2*   meta  = (float2*)(ws + 5 * NN + 64);
    unsigned* xTb   = (unsigned*)(ws + 5 * NN + 64 + 2 * NE);
    float*    M2    = ws + 5 * NN + 64 + 2 * NE + NN * 96;
    float*    B2    = M2 + WT * 3 * CI * CO;
    float*    xagg  = B2 + WT * CO;

    hipMemsetAsync(d_ws, 0, (size_t)(3 * NN + 64) * sizeof(float), stream);

    k_xpose   <<<(NN * 96) / 256, 256, 0, stream>>>(x, xTb);
    k_count   <<<(NE + 255) / 256, 256, 0, stream>>>(A, ew, cnt, deg);
    k_dis_alloc<<<(NN + 255) / 256, 256, 0, stream>>>(deg, cnt, dis, start, total);
    k_scatter <<<(NE + 255) / 256, 256, 0, stream>>>(A, ew, dis, start, fill, meta);
    k_agg     <<<NN / 4, 256, 0, stream>>>(xTb, start, cnt, meta, xagg);
    k_foldW   <<<(WT * 3 * CI * CO + 255) / 256, 256, 0, stream>>>(gw, cw, M2);
    k_foldB   <<<(WT * CO + 255) / 256, 256, 0, stream>>>(gb, cw, cb, B2);
    k_out     <<<(NN + 63) / 64, 64, 0, stream>>>(xagg, M2, B2, out);
}

// Round 3
// 622.946 us; speedup vs baseline: 1.5567x; 1.1441x over previous
//
#include <hip/hip_runtime.h>

#define NN 100000
#define NE 1600000
#define WT 12
#define CI 16
#define CM 32
#define CO 32

#define FXS 33554432.0f   // 2^25 fixed-point scale for deg

// ---- bf16 pack (round-to-nearest-even), 2 channels per uint ---------------
__device__ __forceinline__ unsigned bf16pack(float a, float b) {
    unsigned ua = __float_as_uint(a);
    unsigned ub = __float_as_uint(b);
    ua = (ua + 0x7FFFu + ((ua >> 16) & 1u)) >> 16;
    ub = (ub + 0x7FFFu + ((ub >> 16) & 1u)) >> 16;
    return ua | (ub << 16);
}

// ---------------- K0: transpose x [t][n][ci] -> xTb [n][96 uints] ----------
__global__ void k_xpose(const float* __restrict__ x, unsigned* __restrict__ xTb) {
    int f = blockIdx.x * 256 + threadIdx.x;            // over NN*96
    if (f >= NN * 96) return;
    int n = f / 96;
    int u = f - n * 96;
    int t = u >> 3;
    int p = u & 7;
    const float2* x2 = (const float2*)x;
    float2 v = x2[((size_t)t * NN + n) * 8 + p];
    xTb[f] = bf16pack(v.x, v.y);
}

// ---------------- K1: ONE packed 64-bit atomic per edge --------------------
// pk[c] bits 40+: count; bits 0..39: fixed-point weighted degree (ew * 2^25).
// Returned old value gives this edge's rank within its destination.
__global__ void k_count(const int* __restrict__ A, const float* __restrict__ ew,
                        unsigned long long* __restrict__ pk, int* __restrict__ rank) {
    int e = blockIdx.x * 256 + threadIdx.x;
    if (e >= NE) return;
    int c = A[NE + e];
    unsigned long long fx = (unsigned long long)(ew[e] * FXS + 0.5f);
    unsigned long long old = atomicAdd(&pk[c], (1ull << 40) | fx);
    rank[e] = (int)(old >> 40);
}

// ---------------- K2: dis = rsqrt(deg), segment allocation (wave-scan) -----
// ds[n] = {start, cnt}; dis[n] = deg>0 ? rsqrt(deg) : 0
__global__ void k_dis_alloc(const unsigned long long* __restrict__ pk,
                            float* __restrict__ dis, int2* __restrict__ ds,
                            int* __restrict__ total) {
    int n = blockIdx.x * 256 + threadIdx.x;
    bool valid = (n < NN);
    int c = 0;
    if (valid) {
        unsigned long long v = pk[n];
        c = (int)(v >> 40);
        float d = (float)(v & ((1ull << 40) - 1)) * (1.0f / FXS);
        dis[n] = d > 0.0f ? rsqrtf(d) : 0.0f;
    }
    int lane = threadIdx.x & 63;
    int inc = c;
    #pragma unroll
    for (int o = 1; o < 64; o <<= 1) {
        int v = __shfl_up(inc, o, 64);
        if (lane >= o) inc += v;
    }
    int base = 0;
    if (lane == 63) base = atomicAdd(total, inc);   // one atomic per wave
    base = __shfl(base, 63, 64);
    if (valid) ds[n] = make_int2(base + inc - c, c);
}

// ---------------- K3: atomic-free scatter ----------------------------------
// meta[p] = {src, dis[src]*ew}; dis[dst] applied at end of k_agg instead.
__global__ void k_scatter(const int* __restrict__ A, const float* __restrict__ ew,
                          const float* __restrict__ dis, const int2* __restrict__ ds,
                          const int* __restrict__ rank, float2* __restrict__ meta) {
    int e = blockIdx.x * 256 + threadIdx.x;
    if (e >= NE) return;
    int r = A[e];
    int c = A[NE + e];
    float w = dis[r] * ew[e];
    int p = ds[c].x + rank[e];
    meta[p] = make_float2(__int_as_float(r), w);
}

// ---------------- K4: aggregation, one wave per dst node -------------------
// Lane l<48 loads uint2 -> whole 384B bf16 row in ONE coalesced dwordx2.
// 4 fp32 accs/lane (flat channels 4l..4l+3); dis[node] applied once at end.
__global__ __launch_bounds__(256) void k_agg(const unsigned* __restrict__ xTb,
                      const int2* __restrict__ ds, const float* __restrict__ dis,
                      const float2* __restrict__ meta, float* __restrict__ xagg) {
    int wave = threadIdx.x >> 6;
    int lane = threadIdx.x & 63;
    int node = blockIdx.x * 4 + wave;
    int2 sc = ds[node];
    int s = __builtin_amdgcn_readfirstlane(sc.x);   // force scalar -> s_load meta
    int c = __builtin_amdgcn_readfirstlane(sc.y);
    int li = lane < 48 ? lane : 47;                 // clamp: same cache line, no branch
    float4 acc = make_float4(0.f, 0.f, 0.f, 0.f);
    const float2* mp = meta + s;
    #pragma unroll 4
    for (int i = 0; i < c; i++) {
        float2 m = mp[i];                           // wave-uniform -> scalar load
        int src = __float_as_int(m.x);
        float w = m.y;
        uint2 u = ((const uint2*)(xTb + (size_t)src * 96))[li];
        acc.x += w * __uint_as_float(u.x << 16);
        acc.y += w * __uint_as_float(u.x & 0xFFFF0000u);
        acc.z += w * __uint_as_float(u.y << 16);
        acc.w += w * __uint_as_float(u.y & 0xFFFF0000u);
    }
    float dn = dis[node];
    acc.x *= dn; acc.y *= dn; acc.z *= dn; acc.w *= dn;
    if (lane < 48)
        ((float4*)(xagg + (size_t)node * 192))[lane] = acc;
}

// ---------------- K5a: fold GCN weight into conv weight --------------------
__global__ void k_foldW(const float* __restrict__ gw, const float* __restrict__ cw,
                        float* __restrict__ M2) {
    int i = blockIdx.x * 256 + threadIdx.x;
    if (i >= WT * 3 * CI * CO) return;
    int co = i & 31;
    int rem = i >> 5;            // t*48 + k*16 + ci
    int ci = rem & 15;
    int kidx = rem % 48;
    int k = kidx >> 4;
    int t = rem / 48;
    int tp = t + k - 1;
    float s = 0.0f;
    if (tp >= 0 && tp < WT) {
        for (int cm = 0; cm < CM; cm++)
            s += gw[(tp * CI + ci) * CM + cm] * cw[co * (CM * 3) + cm * 3 + k];
    }
    M2[i] = s;
}

// ---------------- K5b: fold biases -----------------------------------------
__global__ void k_foldB(const float* __restrict__ gb, const float* __restrict__ cw,
                        const float* __restrict__ cb, float* __restrict__ B2) {
    int i = blockIdx.x * 256 + threadIdx.x;
    if (i >= WT * CO) return;
    int co = i & 31;
    int t = i >> 5;
    float s = cb[co];
    for (int k = 0; k < 3; k++) {
        int tp = t + k - 1;
        if (tp < 0 || tp >= WT) continue;
        for (int cm = 0; cm < CM; cm++)
            s += gb[tp * CM + cm] * cw[co * (CM * 3) + cm * 3 + k];
    }
    B2[i] = s;
}

// ---------------- K7: all-t GEMM epilogue, scalar weights, no LDS ----------
__global__ __launch_bounds__(64) void k_out(const float* __restrict__ xagg,
                                            const float* __restrict__ M2,
                                            const float* __restrict__ B2,
                                            float* __restrict__ out) {
    int n = blockIdx.x * 64 + threadIdx.x;
    if (n >= NN) return;
    const float4* xr = (const float4*)(xagg + (size_t)n * 192);
    float prv[16], cur[16], nxt[16];
    #pragma unroll
    for (int j = 0; j < 16; j++) prv[j] = 0.0f;
    #pragma unroll
    for (int q = 0; q < 4; q++) {
        float4 v = xr[q];
        cur[4*q] = v.x; cur[4*q+1] = v.y; cur[4*q+2] = v.z; cur[4*q+3] = v.w;
    }
    #pragma unroll
    for (int q = 0; q < 4; q++) {
        float4 v = xr[4 + q];
        nxt[4*q] = v.x; nxt[4*q+1] = v.y; nxt[4*q+2] = v.z; nxt[4*q+3] = v.w;
    }
    #pragma unroll 1
    for (int t = 0; t < WT; t++) {
        const float* Wt = M2 + (size_t)t * 48 * CO;     // uniform -> s_load
        float acc[CO];
        #pragma unroll
        for (int co = 0; co < CO; co++) acc[co] = B2[t * CO + co];
        #pragma unroll
        for (int j = 0; j < 16; j++) {
            float a = prv[j];
            #pragma unroll
            for (int co = 0; co < CO; co++) acc[co] += a * Wt[j * CO + co];
        }
        #pragma unroll
        for (int j = 0; j < 16; j++) {
            float a = cur[j];
            #pragma unroll
            for (int co = 0; co < CO; co++) acc[co] += a * Wt[(16 + j) * CO + co];
        }
        #pragma unroll
        for (int j = 0; j < 16; j++) {
            float a = nxt[j];
            #pragma unroll
            for (int co = 0; co < CO; co++) acc[co] += a * Wt[(32 + j) * CO + co];
        }
        float* o = out + ((size_t)n * WT + t) * CO;
        #pragma unroll
        for (int co = 0; co < CO; co += 4) {
            float4 v;
            v.x = acc[co]     >= 0.0f ? acc[co]     : 0.01f * acc[co];
            v.y = acc[co + 1] >= 0.0f ? acc[co + 1] : 0.01f * acc[co + 1];
            v.z = acc[co + 2] >= 0.0f ? acc[co + 2] : 0.01f * acc[co + 2];
            v.w = acc[co + 3] >= 0.0f ? acc[co + 3] : 0.01f * acc[co + 3];
            *(float4*)(o + co) = v;
        }
        #pragma unroll
        for (int j = 0; j < 16; j++) { prv[j] = cur[j]; cur[j] = nxt[j]; }
        if (t < WT - 2) {
            #pragma unroll
            for (int q = 0; q < 4; q++) {
                float4 v = xr[(t + 2) * 4 + q];
                nxt[4*q] = v.x; nxt[4*q+1] = v.y; nxt[4*q+2] = v.z; nxt[4*q+3] = v.w;
            }
        } else {
            #pragma unroll
            for (int j = 0; j < 16; j++) nxt[j] = 0.0f;
        }
    }
}

// ---------------- launch ----------------------------------------------------
extern "C" void kernel_launch(void* const* d_in, const int* in_sizes, int n_in,
                              void* d_out, int out_size, void* d_ws, size_t ws_size,
                              hipStream_t stream) {
    const float* x  = (const float*)d_in[0];
    const int*   A  = (const int*)d_in[1];
    const float* ew = (const float*)d_in[2];
    const float* gw = (const float*)d_in[3];
    const float* gb = (const float*)d_in[4];
    const float* cw = (const float*)d_in[5];
    const float* cb = (const float*)d_in[6];
    float* out = (float*)d_out;
    float* ws  = (float*)d_ws;

    // ws layout (float offsets):
    // [pk 2N (u64)][total 16][rank E][dis N][ds 2N (int2)]
    // [meta 2E (float2)][xTb N*96 (uint)][M2 18432][B2 384][xagg N*192]
    unsigned long long* pk = (unsigned long long*)ws;
    int*      total = (int*)(ws + 2 * NN);
    int*      rank  = (int*)(ws + 2 * NN + 16);
    float*    dis   = ws + 2 * NN + 16 + NE;
    int2*     ds    = (int2*)(ws + 3 * NN + 16 + NE);
    float2*   meta  = (float2*)(ws + 5 * NN + 16 + NE);
    unsigned* xTb   = (unsigned*)(ws + 5 * NN + 16 + 3 * NE);
    float*    M2    = ws + 5 * NN + 16 + 3 * NE + NN * 96;
    float*    B2    = M2 + WT * 3 * CI * CO;
    float*    xagg  = B2 + WT * CO;

    // zero pk + total
    hipMemsetAsync(d_ws, 0, (size_t)(2 * NN + 16) * sizeof(float), stream);

    k_xpose    <<<(NN * 96) / 256, 256, 0, stream>>>(x, xTb);
    k_count    <<<(NE + 255) / 256, 256, 0, stream>>>(A, ew, pk, rank);
    k_dis_alloc<<<(NN + 255) / 256, 256, 0, stream>>>(pk, dis, ds, total);
    k_scatter  <<<(NE + 255) / 256, 256, 0, stream>>>(A, ew, dis, ds, rank, meta);
    k_agg      <<<NN / 4, 256, 0, stream>>>(xTb, ds, dis, meta, xagg);
    k_foldW    <<<(WT * 3 * CI * CO + 255) / 256, 256, 0, stream>>>(gw, cw, M2);
    k_foldB    <<<(WT * CO + 255) / 256, 256, 0, stream>>>(gb, cw, cb, B2);
    k_out      <<<(NN + 63) / 64, 64, 0, stream>>>(xagg, M2, B2, out);
}